// Round 16
// baseline (534.000 us; speedup 1.0000x reference)
//
#include <hip/hip_runtime.h>
#include <math.h>

// ws layout (float offsets)
#define SB_OFF   0          // strip records [2][256][1024] = 524288 floats (2.1 MB)
#define E_OFF    524288     // e [128][2048] = 262144 floats
#define PT_OFF   786432     // ready tags: 256 x 16 uints (64B padded)
// record (1024 floats): un-tagged f4 payload + per-wave tags
//   HT[4][32]@0  HB[4][32]@128  VL[64][4]@256  VR[64][4]@512
//   CTL[4][4]@768 CTR@784 CBL@800 CBR@816   tags[8] @832 (stride 16 floats)

typedef float vf4 __attribute__((ext_vector_type(4)));

__device__ __forceinline__ float fast_tanh(float x) {
  x = fminf(fmaxf(x, -15.f), 15.f);
  float ex = __expf(2.f * x);
  return __fdividef(ex - 1.f, ex + 1.f);
}

template <int CTRL>
__device__ __forceinline__ float dpp_add(float v) {
  int x = __builtin_amdgcn_update_dpp(0, __float_as_int(v), CTRL, 0xF, 0xF, true);
  return v + __int_as_float(x);
}

// coherent-point (sc0 sc1) accessors — L1/L2 bypass, cross-XCD visible
__device__ __forceinline__ void st16(float* p, float a, float b, float c, float d) {
  vf4 v; v.x = a; v.y = b; v.z = c; v.w = d;
  asm volatile("global_store_dwordx4 %0, %1, off sc0 sc1" :: "v"(p), "v"(v) : "memory");
}
__device__ __forceinline__ void stc(float* p, float v) {
  asm volatile("global_store_dword %0, %1, off sc0 sc1" :: "v"(p), "v"(v) : "memory");
}
__device__ __forceinline__ vf4 ld16(const float* p) {
  vf4 r;
  asm volatile("global_load_dwordx4 %0, %1, off sc0 sc1\n"
               "s_waitcnt vmcnt(0)"
               : "=&v"(r) : "v"(p) : "memory");
  return r;
}
// wave-level release: drain this wave's stores, THEN publish the tag.
__device__ __forceinline__ void tag_store(unsigned* p, unsigned v) {
  asm volatile("s_waitcnt vmcnt(0)\n"
               "global_store_dword %0, %1, off sc0 sc1" :: "v"(p), "v"(v) : "memory");
}

// ---------------- single kernel: phase P (embed + bias init) then r13 scan
__global__ __launch_bounds__(512, 2) void scan_kernel(
    const float* __restrict__ X, const float* __restrict__ W_embed,
    const float* __restrict__ mask_coarse, const float* __restrict__ b_out,
    const float* __restrict__ mask_fine, const float* __restrict__ W_deconv,
    const float* __restrict__ w1, const float* __restrict__ w2,
    const float* __restrict__ w_out, float* __restrict__ ws,
    float* __restrict__ out)
{
  __shared__ float zin[2][72 * 44];     // Z parity buffers, tile + 4-halo
  __shared__ float rowbuf[2][64 * 17];  // readout partials, parity
  __shared__ float Xl[128][36];         // phase P: X chunk (128 t x 32 k)
  __shared__ float Wl[8][36];           // phase P: W chunk (8 o x 32 k)

  const int tid  = threadIdx.x;       // 0..511
  const int bid  = blockIdx.x;
  float* Zb = ws + SB_OFF;
  float* eb = ws + E_OFF;
  unsigned* ptag = (unsigned*)(ws + PT_OFF);

  // ======== PHASE P: e rows 8*bid..8*bid+7 (all t) + bias-init out slice
  {
    const int ol = tid & 7;           // o-local 0..7
    const int tg = tid >> 3;          // t-group 0..63 (2 t each)
    float acc0 = 0.f, acc1 = 0.f;
    for (int k0 = 0; k0 < 512; k0 += 32) {
      __syncthreads();
#pragma unroll
      for (int q = 0; q < 2; ++q) {
        int u = tid + q * 512;        // coalesced: 8 lanes cover 32 consecutive k
        int xr = u >> 3, kc = (u & 7) << 2;
        *(float4*)&Xl[xr][kc] = *(const float4*)&X[(size_t)xr * 512 + k0 + kc];
      }
      if (tid < 64) {
        int wr = tid >> 3, wc = (tid & 7) << 2;
        *(float4*)&Wl[wr][wc] = *(const float4*)&W_embed[(size_t)(bid * 8 + wr) * 512 + k0 + wc];
      }
      __syncthreads();
#pragma unroll
      for (int kk = 0; kk < 8; ++kk) {
        float4 w4 = *(const float4*)&Wl[ol][kk * 4];
        float4 x0 = *(const float4*)&Xl[tg * 2 + 0][kk * 4];
        float4 x1 = *(const float4*)&Xl[tg * 2 + 1][kk * 4];
        acc0 = fmaf(w4.x, x0.x, fmaf(w4.y, x0.y, fmaf(w4.z, x0.z, fmaf(w4.w, x0.w, acc0))));
        acc1 = fmaf(w4.x, x1.x, fmaf(w4.y, x1.y, fmaf(w4.z, x1.z, fmaf(w4.w, x1.w, acc1))));
      }
    }
    const int o = bid * 8 + ol;
    float mc = mask_coarse[o & 255];
    stc(eb + (size_t)(tg * 2 + 0) * 2048 + o, acc0 * mc);
    stc(eb + (size_t)(tg * 2 + 1) * 2048 + o, acc1 * mc);
    if (tid < 128) {                  // bias-init out[bid*512 .. +512)
      int idx = bid * 512 + tid * 4;
      float b = b_out[(idx >> 6) & 15];
      st16(out + idx, b, b, b, b);
    }
    asm volatile("s_waitcnt vmcnt(0)" ::: "memory");  // every wave drains its stores
    __syncthreads();
    if (tid == 0) tag_store(ptag + bid * 16, 1u);
    // all-ready poll (each thread one producer), then one-time cache invalidate
    if (tid < 256) {
      int spins = 0;
      while (__hip_atomic_load(ptag + tid * 16, __ATOMIC_RELAXED,
                               __HIP_MEMORY_SCOPE_AGENT) != 1u) {
        __builtin_amdgcn_s_sleep(2);
        if (++spins > (1 << 20)) break;  // fail loud (wrong), never hang
      }
    }
    __syncthreads();
    __threadfence();   // one-time L2/L1 invalidate: plain eb loads are now safe
    __syncthreads();
  }

  // ======== r13-exact scan
  const int ch   = bid >> 5;
  const int tile = bid & 31;
  const int tI = tile >> 3, tJ = tile & 7;
  const int r0 = tI << 6, c0 = tJ << 5;
  const int row = tid >> 3;           // 0..63
  const int cg  = tid & 7;
  const int lc  = cg << 2;
  const int myoff = (ch * 32 + tile) << 10;   // record stride 1024

  const int i0 = (r0 + row) >> 4;
  const int jj = (c0 + lc) >> 4;
  float4 wd[8];
#pragma unroll
  for (int c = 0; c < 8; ++c)
    wd[c] = *(const float4*)&W_deconv[(((c * 8 + ch) * 16) + (row & 15)) * 16 + (lc & 15)];
  float4 mf = *(const float4*)&mask_fine[(size_t)(r0 + row) * 256 + c0 + lc];
  float4 wo[16];
#pragma unroll
  for (int oc = 0; oc < 16; ++oc)
    wo[oc] = *(const float4*)&w_out[(((oc * 8 + ch) * 32) + (row & 31)) * 32 + lc];
  float w1s[9], w2s[25];
#pragma unroll
  for (int k = 0; k < 9; ++k)
    w1s[k] = __uint_as_float(__builtin_amdgcn_readfirstlane(__float_as_uint(w1[ch * 9 + k])));
#pragma unroll
  for (int k = 0; k < 25; ++k)
    w2s[k] = __uint_as_float(__builtin_amdgcn_readfirstlane(__float_as_uint(w2[ch * 25 + k])));

  // fixed halo-read assignment: 208 f4 chunks; 1 per thread (tid<208)
  int rd_src = 0, rd_dst = 0, rd_tag = 0;
  const bool hasrd = (tid < 208);
  if (hasrd) {
    int u = tid, di = 0, dj = 0, src = 0, dst = 0, wv = 0;
    if (u < 32) {              // top rows 0..3 <- U.HB (U wave 7)
      di = -1; src = 128 + (u >> 3) * 32 + (u & 7) * 4;
      dst = (u >> 3) * 44 + 4 + (u & 7) * 4; wv = 7;
    } else if (u < 64) {       // bottom rows 68..71 <- D.HT (D wave 0)
      int v = u - 32; di = 1; src = (v >> 3) * 32 + (v & 7) * 4;
      dst = (68 + (v >> 3)) * 44 + 4 + (v & 7) * 4; wv = 0;
    } else if (u < 128) {      // left rows 4..67 <- L.VR (L wave v/8)
      int v = u - 64; dj = -1; src = 512 + v * 4; dst = (4 + v) * 44; wv = v >> 3;
    } else if (u < 192) {      // right rows 4..67 <- R.VL (R wave v/8)
      int v = u - 128; dj = 1; src = 256 + v * 4; dst = (4 + v) * 44 + 36; wv = v >> 3;
    } else {                   // corners, 4 chunks each
      int v = u - 192, c = v >> 2, r = v & 3;
      if (c == 0)      { di = -1; dj = -1; src = 816 + r * 4; dst = r * 44;            wv = 7; }
      else if (c == 1) { di = -1; dj = 1;  src = 800 + r * 4; dst = r * 44 + 36;       wv = 7; }
      else if (c == 2) { di = 1;  dj = -1; src = 784 + r * 4; dst = (68 + r) * 44;     wv = 0; }
      else             { di = 1;  dj = 1;  src = 768 + r * 4; dst = (68 + r) * 44 + 36; wv = 0; }
    }
    int nI = (tI + di) & 3, nJ = (tJ + dj) & 7;
    int roff = (ch * 32 + nI * 8 + nJ) << 10;
    rd_src = roff + src;
    rd_tag = roff + 832 + wv * 16;
    rd_dst = dst;
  }

  // init both parity buffers (Z0 = 0, incl. halo)
  for (int k = tid; k < 2 * 72 * 44; k += 512) zin[0][k] = 0.f;
  __syncthreads();

  for (int t = 0; t < 128; ++t) {
    float* sb = Zb + (size_t)((t + 1) & 1) * 262144;   // records for Z_{t+1}
    const float* zr = zin[t & 1];
    float*       zw = zin[(t + 1) & 1];
    float*       rb = rowbuf[t & 1];

    // input-path e values (plain cached loads; safe post-fence, read-only)
    float ev[8];
#pragma unroll
    for (int c = 0; c < 8; ++c)
      ev[c] = eb[(size_t)t * 2048 + c * 256 + i0 * 16 + jj];

    // ---- compute Z_{t+1} for this thread's 4 px (reads zr = Z_t incl halo)
    float c1a[4] = {0, 0, 0, 0}, c2a[4] = {0, 0, 0, 0};
    {
      float w[12];
      auto load_row = [&](int zrr) {
        float4 A  = *(const float4*)&zr[zrr * 44 + lc];
        float4 B  = *(const float4*)&zr[zrr * 44 + lc + 4];
        float4 Cq = *(const float4*)&zr[zrr * 44 + lc + 8];
        w[0]=A.x; w[1]=A.y; w[2]=A.z; w[3]=A.w;
        w[4]=B.x; w[5]=B.y; w[6]=B.z; w[7]=B.w;
        w[8]=Cq.x; w[9]=Cq.y; w[10]=Cq.z; w[11]=Cq.w;
      };
      auto k2row = [&](int a) {
#pragma unroll
        for (int j = 0; j < 4; ++j)
#pragma unroll
          for (int b = 0; b < 5; ++b)
            c2a[j] = fmaf(w[j + 2 * b], w2s[a * 5 + b], c2a[j]);
      };
      auto k1row = [&](int a) {
#pragma unroll
        for (int j = 0; j < 4; ++j)
#pragma unroll
          for (int b = 0; b < 3; ++b)
            c1a[j] = fmaf(w[j + 3 + b], w1s[a * 3 + b], c1a[j]);
      };
      load_row(row + 0); k2row(0);
      load_row(row + 2); k2row(1);
      load_row(row + 3); k1row(0);
      load_row(row + 4); k1row(1); k2row(2);
      load_row(row + 5); k1row(2);
      load_row(row + 6); k2row(3);
      load_row(row + 8); k2row(4);
    }
    float zv[4];
    {
      const float* mfp = (const float*)&mf;
#pragma unroll
      for (int j = 0; j < 4; ++j) {
        float u = 0.f;
#pragma unroll
        for (int c = 0; c < 8; ++c)
          u = fmaf(ev[c], ((const float*)&wd[c])[j], u);
        float val = fmaf(0.9f, c1a[j], fmaf(0.1f, c2a[j], mfp[j] * u));
        zv[j] = fast_tanh(val);
      }
    }

    // ---- publish packed 16B boundary chunks, then per-wave release tag
    if (t < 127) {
      float* rec = sb + myoff;
      if (row < 4)   st16(rec + row * 32 + lc, zv[0], zv[1], zv[2], zv[3]);            // HT
      if (row >= 60) st16(rec + 128 + (row - 60) * 32 + lc, zv[0], zv[1], zv[2], zv[3]); // HB
      if (lc == 0)   st16(rec + 256 + row * 4, zv[0], zv[1], zv[2], zv[3]);            // VL
      if (lc == 28)  st16(rec + 512 + row * 4, zv[0], zv[1], zv[2], zv[3]);            // VR
      if (row < 4 && lc == 0)   st16(rec + 768 + row * 4, zv[0], zv[1], zv[2], zv[3]); // CTL
      if (row < 4 && lc == 28)  st16(rec + 784 + row * 4, zv[0], zv[1], zv[2], zv[3]); // CTR
      if (row >= 60 && lc == 0) st16(rec + 800 + (row - 60) * 4, zv[0], zv[1], zv[2], zv[3]); // CBL
      if (row >= 60 && lc == 28) st16(rec + 816 + (row - 60) * 4, zv[0], zv[1], zv[2], zv[3]); // CBR
      if ((tid & 63) == 0)
        tag_store((unsigned*)(rec + 832 + (tid >> 6) * 16), (unsigned)(t + 1));
    }

    // ---- commit interior into the OTHER parity buffer
    *(float4*)&zw[(4 + row) * 44 + 4 + lc] = make_float4(zv[0], zv[1], zv[2], zv[3]);

    // ---- readout FMAs + octet DPP reduce -> rowbuf[parity]
    float racc[16];
#pragma unroll
    for (int oc = 0; oc < 16; ++oc) {
      const float* wop = (const float*)&wo[oc];
      racc[oc] = fmaf(zv[0], wop[0], fmaf(zv[1], wop[1], fmaf(zv[2], wop[2], zv[3] * wop[3])));
    }
#pragma unroll
    for (int k = 0; k < 16; ++k) {
      racc[k] = dpp_add<0xB1>(racc[k]);
      racc[k] = dpp_add<0x4E>(racc[k]);
      racc[k] = dpp_add<0x141>(racc[k]);
    }
    rb[row * 17 + (cg << 1)]     = racc[cg << 1];
    rb[row * 17 + (cg << 1) + 1] = racc[(cg << 1) + 1];

    // ---- halo: poll producer-wave tag (acquire), then 16B payload load
    if (t < 127 && hasrd) {
      const unsigned tg = (unsigned)(t + 1);
      const unsigned* ta = (const unsigned*)(sb + rd_tag);
      int spins = 0;
      while (__hip_atomic_load(ta, __ATOMIC_RELAXED, __HIP_MEMORY_SCOPE_AGENT) != tg) {
        __builtin_amdgcn_s_sleep(1);
        if (++spins > (1 << 18)) break;  // fail loud (wrong), never hang
      }
      vf4 v = ld16(sb + rd_src);
      zw[rd_dst]     = v.x;
      zw[rd_dst + 1] = v.y;
      zw[rd_dst + 2] = v.z;
      zw[rd_dst + 3] = v.w;
    }

    __syncthreads();  // the ONE barrier: zw (interior+halo) + rowbuf complete

    // ---- stage 2: fold rowbuf[parity] -> atomicAdd out (bias pre-initialized)
    if (tid < 32) {
      int p = tid >> 4, oc = tid & 15;
      float s = 0.f;
#pragma unroll
      for (int r = 0; r < 32; ++r) s += rb[(p * 32 + r) * 17 + oc];
      atomicAdd(&out[t * 1024 + oc * 64 + (2 * tI + p) * 8 + tJ], s);
    }
  }
}

extern "C" void kernel_launch(void* const* d_in, const int* in_sizes, int n_in,
                              void* d_out, int out_size, void* d_ws, size_t ws_size,
                              hipStream_t stream) {
  const float* X           = (const float*)d_in[0];
  const float* W_embed     = (const float*)d_in[1];
  const float* mask_coarse = (const float*)d_in[2];
  const float* mask_fine   = (const float*)d_in[3];
  const float* W_deconv    = (const float*)d_in[4];
  const float* w1          = (const float*)d_in[5];
  const float* w2          = (const float*)d_in[6];
  const float* w_out       = (const float*)d_in[7];
  const float* b_out       = (const float*)d_in[8];
  float* ws  = (float*)d_ws;
  float* out = (float*)d_out;

  scan_kernel<<<dim3(256), dim3(512), 0, stream>>>(
      X, W_embed, mask_coarse, b_out, mask_fine, W_deconv, w1, w2, w_out, ws, out);
}